// Round 8
// baseline (177.896 us; speedup 1.0000x reference)
//
#include <hip/hip_runtime.h>

#define Mdim 8
#define Tdim 4000
#define Bdim 128
#define Hdim 512
#define NPER (Tdim*Hdim)
#define EPSG 1e-8f

typedef __attribute__((ext_vector_type(8))) short short8;
typedef __attribute__((ext_vector_type(4))) float floatx4;

static __device__ __forceinline__ float bits2f(unsigned short s) {
  union { unsigned int u; float f; } v; v.u = ((unsigned int)s) << 16; return v.f;
}
static __device__ __forceinline__ unsigned short f2bits(float f) {
  union { float f; unsigned int u; } v; v.f = f;
  unsigned int u = v.u;
  u += 0x7fffu + ((u >> 16) & 1u);   // RNE
  return (unsigned short)(u >> 16);
}
static __device__ __forceinline__ short8 pack8(const float4& a, const float4& b) {
  short8 v;
  v[0]=(short)f2bits(a.x); v[1]=(short)f2bits(a.y); v[2]=(short)f2bits(a.z); v[3]=(short)f2bits(a.w);
  v[4]=(short)f2bits(b.x); v[5]=(short)f2bits(b.y); v[6]=(short)f2bits(b.z); v[7]=(short)f2bits(b.w);
  return v;
}

// ---------------- K0: stats-independent prep: W2raw = g2*pw (bf16, [B,H]), dotg2[b]=sum g2*pw, dotb2[b]=sum b2*pw
__global__ __launch_bounds__(64) void k_prep(
    const float* __restrict__ g2w,
    const float* __restrict__ b2w,
    const float* __restrict__ pww,
    unsigned short* __restrict__ W2raw,
    float* __restrict__ dotg2,
    float* __restrict__ dotb2)
{
  const int b = blockIdx.x, tid = threadIdx.x;
  const int j8 = tid*8;
  float g2v[8], b2v[8], pv[8];
  #pragma unroll
  for (int j = 0; j < 8; j += 4) {
    *(float4*)&g2v[j] = *(const float4*)&g2w[j8 + j];
    *(float4*)&b2v[j] = *(const float4*)&b2w[j8 + j];
    *(float4*)&pv[j]  = *(const float4*)&pww[(size_t)b*Hdim + j8 + j];
  }
  float dg = 0.f, db = 0.f;
  short8 wv8;
  #pragma unroll
  for (int j = 0; j < 8; ++j) {
    dg = fmaf(g2v[j], pv[j], dg);
    db = fmaf(b2v[j], pv[j], db);
    wv8[j] = (short)f2bits(g2v[j]*pv[j]);
  }
  *(short8*)&W2raw[(size_t)b*Hdim + j8] = wv8;
  #pragma unroll
  for (int st = 32; st > 0; st >>= 1) { dg += __shfl_xor(dg, st); db += __shfl_xor(db, st); }
  if (tid == 0) { dotg2[b] = dg; dotb2[b] = db; }
}

// ---------------- K1: conv1 GEMM + PReLU + gLN1 partials -> Hbuf [M,T,H] bf16
// 32-row t-tiles: grid (125, 2 h-halves, 8 m) = 2000 blocks (~8/CU). No bounds checks (125*32=4000).
__global__ __launch_bounds__(256) void k_conv1(
    const float* __restrict__ x,
    const float* __restrict__ w1,
    const float* __restrict__ a1p,
    unsigned short* __restrict__ Hbuf,
    float2* __restrict__ part1)
{
  __shared__ __align__(16) unsigned short ldsW[64*136];
  __shared__ __align__(16) unsigned short ltile[32*72];
  __shared__ float red[512];

  const int tid = threadIdx.x;
  const int t0 = blockIdx.x * 32;
  const int hh = blockIdx.y;         // h-half (256 cols each)
  const int m  = blockIdx.z;

  const int lane = tid & 63, wv = tid >> 6, quad = lane >> 4, l16 = lane & 15;
  const int rowHalf = wv & 1, nHalf = wv >> 1;
  const int tr = t0 + rowHalf*16 + l16;
  const float* xrow = x + ((size_t)m*Tdim + tr)*Bdim;
  short8 afr[4];
  #pragma unroll
  for (int ks = 0; ks < 4; ++ks) {
    float4 fa = *(const float4*)&xrow[ks*32 + quad*8];
    float4 fb = *(const float4*)&xrow[ks*32 + quad*8 + 4];
    afr[ks] = pack8(fa, fb);
  }

  const float a1 = a1p[0];
  float lsum = 0.f, lss = 0.f;

  for (int hc = 0; hc < 4; ++hc) {
    const int h0 = hh*256 + hc*64;
    __syncthreads();   // previous ltile/ldsW consumers done
    #pragma unroll
    for (int it = 0; it < 4; ++it) {
      int idx = (it*256 + tid) * 8;
      int r = idx >> 7, c = idx & 127;
      float4 fa = *(const float4*)&w1[(size_t)(h0 + r)*Bdim + c];
      float4 fb = *(const float4*)&w1[(size_t)(h0 + r)*Bdim + c + 4];
      *(short8*)&ldsW[r*136 + c] = pack8(fa, fb);
    }
    __syncthreads();

    floatx4 acc[2] = {};
    #pragma unroll
    for (int ks = 0; ks < 4; ++ks) {
      #pragma unroll
      for (int nt = 0; nt < 2; ++nt) {
        short8 bfr = *(const short8*)&ldsW[(nHalf*32 + nt*16 + l16)*136 + ks*32 + quad*8];
        acc[nt] = __builtin_amdgcn_mfma_f32_16x16x32_bf16(afr[ks], bfr, acc[nt], 0, 0, 0);
      }
    }

    #pragma unroll
    for (int nt = 0; nt < 2; ++nt) {
      int hl = nHalf*32 + nt*16 + l16;      // C/D: col = lane&15
      #pragma unroll
      for (int r = 0; r < 4; ++r) {
        int tl = rowHalf*16 + quad*4 + r;   // C/D: row = quad*4+reg
        float v = acc[nt][r];
        v = v >= 0.f ? v : a1 * v;
        lsum += v; lss += v*v;
        ltile[tl*72 + hl] = f2bits(v);
      }
    }
    __syncthreads();
    {
      int tr2 = tid >> 3, ck = (tid & 7) * 8;
      unsigned short* dst = &Hbuf[((size_t)m*Tdim + t0 + tr2)*Hdim + h0 + ck];
      *(short8*)&dst[0] = *(const short8*)&ltile[tr2*72 + ck];
    }
  }

  red[tid] = lsum; red[256 + tid] = lss;
  __syncthreads();
  for (int s = 128; s > 0; s >>= 1) {
    if (tid < s) { red[tid] += red[tid + s]; red[256+tid] += red[256+tid+s]; }
    __syncthreads();
  }
  if (tid == 0)
    part1[((size_t)m*2 + hh)*125 + blockIdx.x] = make_float2(red[0], red[256]);
}

// ---------------- K2: fused offsets + deformable dw conv + PReLU2 + gLN2 partials -> Ybuf [M,T,H] bf16
__global__ __launch_bounds__(256) void k_deform(
    const unsigned short* __restrict__ Hbuf,
    const float2* __restrict__ part1,
    const float* __restrict__ g1w,
    const float* __restrict__ b1w,
    const float* __restrict__ odw,
    const float* __restrict__ aodcp,
    const float* __restrict__ opw,
    const float* __restrict__ aopcp,
    const float* __restrict__ dww,
    const float* __restrict__ dwb,
    const float* __restrict__ a2p,
    unsigned short* __restrict__ Ybuf,
    float2* __restrict__ part2)
{
  __shared__ float s_stats[2];
  __shared__ float rsum[4], rss[4];
  const int tid = threadIdx.x, lane = tid & 63, w = tid >> 6;
  const int tb = blockIdx.x*8 + w*2;       // grid.x = 500; wave handles t = tb, tb+1
  const int m = blockIdx.y;
  const int c8 = lane*8;
  const unsigned short* base = Hbuf + (size_t)m*Tdim*Hdim;

  // issue offset-branch row loads EARLY (independent of stats barrier)
  short8 hrow[2][3];
  #pragma unroll
  for (int tt = 0; tt < 2; ++tt) {
    int t = tb + tt;
    int tm1 = (t == 0) ? 1 : t-1;
    int tp1 = (t == Tdim-1) ? Tdim-2 : t+1;
    hrow[tt][0] = *(const short8*)&base[(size_t)tm1*Hdim + c8];
    hrow[tt][1] = *(const short8*)&base[(size_t)t  *Hdim + c8];
    hrow[tt][2] = *(const short8*)&base[(size_t)tp1*Hdim + c8];
  }
  float g1v[8], b1v[8];
  #pragma unroll
  for (int j = 0; j < 8; j += 4) {
    *(float4*)&g1v[j] = *(const float4*)&g1w[c8 + j];
    *(float4*)&b1v[j] = *(const float4*)&b1w[c8 + j];
  }

  // inline reduce of part1 (250 entries) -> stats1
  if (tid < 64) {
    float s = 0.f, q = 0.f;
    for (int i = lane; i < 250; i += 64) {
      float2 p = part1[(size_t)m*250 + i];
      s += p.x; q += p.y;
    }
    #pragma unroll
    for (int st = 32; st > 0; st >>= 1) { s += __shfl_xor(s, st); q += __shfl_xor(q, st); }
    if (lane == 0) { s_stats[0] = s; s_stats[1] = q; }
  }
  __syncthreads();
  const float invn = 1.0f/(float)NPER;
  const float mean1 = s_stats[0]*invn;
  const float var1  = fmaxf(s_stats[1]*invn - mean1*mean1, 0.f);
  const float inv1  = 1.0f/sqrtf(var1 + EPSG);

  // ---- offset branch for both t ----
  float oa[2][3] = {};
  {
    const float aodc = aodcp[0];
    float wod[24], q0v[8], q1v[8], q2v[8];
    #pragma unroll
    for (int j = 0; j < 8; j += 4) {
      *(float4*)&q0v[j] = *(const float4*)&opw[c8 + j];
      *(float4*)&q1v[j] = *(const float4*)&opw[Hdim + c8 + j];
      *(float4*)&q2v[j] = *(const float4*)&opw[2*Hdim + c8 + j];
    }
    #pragma unroll
    for (int j = 0; j < 24; j += 4)
      *(float4*)&wod[j] = *(const float4*)&odw[c8*3 + j];

    #pragma unroll
    for (int j = 0; j < 8; ++j) {
      float A = g1v[j] * inv1;
      float C = b1v[j] - mean1*A;
      #pragma unroll
      for (int tt = 0; tt < 2; ++tt) {
        float fm = fmaf(A, bits2f((unsigned short)hrow[tt][0][j]), C);
        float fz = fmaf(A, bits2f((unsigned short)hrow[tt][1][j]), C);
        float fp = fmaf(A, bits2f((unsigned short)hrow[tt][2][j]), C);
        float d = fm*wod[j*3+0] + fz*wod[j*3+1] + fp*wod[j*3+2];
        d = d >= 0.f ? d : aodc*d;
        oa[tt][0] = fmaf(d, q0v[j], oa[tt][0]);
        oa[tt][1] = fmaf(d, q1v[j], oa[tt][1]);
        oa[tt][2] = fmaf(d, q2v[j], oa[tt][2]);
      }
    }
    #pragma unroll
    for (int s = 32; s > 0; s >>= 1) {
      #pragma unroll
      for (int tt = 0; tt < 2; ++tt) {
        oa[tt][0] += __shfl_xor(oa[tt][0], s);
        oa[tt][1] += __shfl_xor(oa[tt][1], s);
        oa[tt][2] += __shfl_xor(oa[tt][2], s);
      }
    }
  }

  // ---- tap params (wave-uniform) + gathers for both t ----
  const float aopc = aopcp[0];
  const float a2   = a2p[0];
  int I0[2][3], I1[2][3]; float G0[2][3], G1[2][3], GS[2][3];
  #pragma unroll
  for (int tt = 0; tt < 2; ++tt) {
    const float tf = (float)(tb + tt);
    #pragma unroll
    for (int k = 0; k < 3; ++k) {
      float off = oa[tt][k];
      off = off >= 0.f ? off : aopc*off;
      float pos = tf + (float)(2*k) + off;
      pos = fminf(fmaxf(pos, tf), tf + 4.0f);
      int U = (int)floorf(pos);
      if (U > Tdim + 2) U = Tdim + 2;        // Lp-2
      float Uf = (float)U;
      G0[tt][k] = fmaxf(0.f, 1.f - fabsf(Uf - pos));
      G1[tt][k] = fmaxf(0.f, 1.f - fabsf(Uf + 1.f - pos));
      GS[tt][k] = G0[tt][k] + G1[tt][k];
      int ia = U - 2; ia = ia < 0 ? -ia : ia; if (ia > Tdim-1) ia = 2*(Tdim-1) - ia;
      int ib = U - 1; ib = ib < 0 ? -ib : ib; if (ib > Tdim-1) ib = 2*(Tdim-1) - ib;
      I0[tt][k] = ia; I1[tt][k] = ib;
    }
  }

  short8 s0v[2][3], s1v[2][3];
  #pragma unroll
  for (int tt = 0; tt < 2; ++tt)
    #pragma unroll
    for (int k = 0; k < 3; ++k) {
      s0v[tt][k] = *(const short8*)&base[(size_t)I0[tt][k]*Hdim + c8];
      s1v[tt][k] = *(const short8*)&base[(size_t)I1[tt][k]*Hdim + c8];
    }

  float bv[8], wd[24];
  #pragma unroll
  for (int j = 0; j < 8; j += 4)
    *(float4*)&bv[j] = *(const float4*)&dwb[c8 + j];
  #pragma unroll
  for (int j = 0; j < 24; j += 4)
    *(float4*)&wd[j] = *(const float4*)&dww[c8*3 + j];

  float lsum = 0.f, lss = 0.f;
  short8 yv[2];
  #pragma unroll
  for (int j = 0; j < 8; ++j) {
    float A = g1v[j] * inv1;
    float C = b1v[j] - mean1*A;
    float w0 = wd[j*3+0], w1 = wd[j*3+1], w2 = wd[j*3+2];
    #pragma unroll
    for (int tt = 0; tt < 2; ++tt) {
      float ybase = fmaf(C, w0*GS[tt][0] + w1*GS[tt][1] + w2*GS[tt][2], bv[j]);
      float t0s = fmaf(G1[tt][0], bits2f((unsigned short)s1v[tt][0][j]), G0[tt][0]*bits2f((unsigned short)s0v[tt][0][j]));
      float t1s = fmaf(G1[tt][1], bits2f((unsigned short)s1v[tt][1][j]), G0[tt][1]*bits2f((unsigned short)s0v[tt][1][j]));
      float t2s = fmaf(G1[tt][2], bits2f((unsigned short)s1v[tt][2][j]), G0[tt][2]*bits2f((unsigned short)s0v[tt][2][j]));
      float acc = w0*t0s + w1*t1s + w2*t2s;
      float y = fmaf(A, acc, ybase);
      float p = y >= 0.f ? y : a2*y;
      lsum += p; lss += p*p;
      yv[tt][j] = (short)f2bits(p);
    }
  }
  #pragma unroll
  for (int tt = 0; tt < 2; ++tt)
    *(short8*)&Ybuf[((size_t)m*Tdim + tb + tt)*Hdim + c8] = yv[tt];

  #pragma unroll
  for (int s = 32; s > 0; s >>= 1) {
    lsum += __shfl_xor(lsum, s);
    lss  += __shfl_xor(lss, s);
  }
  if (lane == 0) { rsum[w] = lsum; rss[w] = lss; }
  __syncthreads();
  if (tid == 0)
    part2[(size_t)m*500 + blockIdx.x] =
      make_float2(rsum[0]+rsum[1]+rsum[2]+rsum[3], rss[0]+rss[1]+rss[2]+rss[3]);
}

// ---------------- K3: final GEMM Ybuf @ W2raw^T, epilogue inv2*acc + const2[b] + x -> out f32
// 32-row t-tiles: grid (125, 2 n-halves, 8 m) = 2000 blocks. stats2 reduced in prologue.
__global__ __launch_bounds__(256) void k_out(
    const unsigned short* __restrict__ Ybuf,
    const unsigned short* __restrict__ W2raw,
    const float2* __restrict__ part2,
    const float* __restrict__ dotg2,
    const float* __restrict__ dotb2,
    const float* __restrict__ x,
    float* __restrict__ out)
{
  __shared__ __align__(16) unsigned short ldsW[64*136];
  __shared__ __align__(16) float ltf[32*68];
  __shared__ float s_stats[2];
  const int tid = threadIdx.x;
  const int t0 = blockIdx.x*32;
  const int n0 = blockIdx.y*64;
  const int m  = blockIdx.z;
  const int lane = tid & 63, wv = tid >> 6, quad = lane >> 4, l16 = lane & 15;
  const int rowHalf = wv & 1, nHalf = wv >> 1;

  // prologue: reduce part2 -> stats2
  if (tid < 64) {
    float s = 0.f, q = 0.f;
    for (int i = lane; i < 500; i += 64) {
      float2 p = part2[(size_t)m*500 + i];
      s += p.x; q += p.y;
    }
    #pragma unroll
    for (int st = 32; st > 0; st >>= 1) { s += __shfl_xor(s, st); q += __shfl_xor(q, st); }
    if (lane == 0) { s_stats[0] = s; s_stats[1] = q; }
  }

  const unsigned short* arow = Ybuf + ((size_t)m*Tdim + t0 + rowHalf*16 + l16)*Hdim;
  floatx4 acc[2] = {};
  for (int kc = 0; kc < 4; ++kc) {
    __syncthreads();
    #pragma unroll
    for (int it = 0; it < 4; ++it) {
      int idx = (it*256 + tid)*8;
      int r = idx >> 7, c = idx & 127;
      *(short8*)&ldsW[r*136 + c] =
        *(const short8*)&W2raw[(size_t)(n0 + r)*Hdim + kc*128 + c];
    }
    __syncthreads();
    #pragma unroll
    for (int ks = 0; ks < 4; ++ks) {
      short8 afr = *(const short8*)&arow[kc*128 + ks*32 + quad*8];
      #pragma unroll
      for (int nt = 0; nt < 2; ++nt) {
        short8 bfr = *(const short8*)&ldsW[(nHalf*32 + nt*16 + l16)*136 + ks*32 + quad*8];
        acc[nt] = __builtin_amdgcn_mfma_f32_16x16x32_bf16(afr, bfr, acc[nt], 0, 0, 0);
      }
    }
  }

  const float invn = 1.0f/(float)NPER;
  const float mean2 = s_stats[0]*invn;
  const float var2  = fmaxf(s_stats[1]*invn - mean2*mean2, 0.f);
  const float inv2  = 1.0f/sqrtf(var2 + EPSG);

  __syncthreads();   // ldsW consumption done
  #pragma unroll
  for (int nt = 0; nt < 2; ++nt) {
    int bl = nHalf*32 + nt*16 + l16;
    int b = n0 + bl;
    float cst = dotb2[b] - mean2*inv2*dotg2[b];
    #pragma unroll
    for (int r = 0; r < 4; ++r) {
      int tl = rowHalf*16 + quad*4 + r;
      ltf[tl*68 + bl] = fmaf(inv2, acc[nt][r], cst);
    }
  }
  __syncthreads();
  {
    int tr2 = tid >> 3, ck = (tid & 7) * 8;
    const float* xr = &x[((size_t)m*Tdim + t0 + tr2)*Bdim + n0 + ck];
    float* orow = &out[((size_t)m*Tdim + t0 + tr2)*Bdim + n0 + ck];
    #pragma unroll
    for (int j = 0; j < 2; ++j) {
      float4 v = *(const float4*)&ltf[tr2*68 + ck + j*4];
      float4 rx = *(const float4*)&xr[j*4];
      v.x += rx.x; v.y += rx.y; v.z += rx.z; v.w += rx.w;
      *(float4*)&orow[j*4] = v;
    }
  }
}

extern "C" void kernel_launch(void* const* d_in, const int* in_sizes, int n_in,
                              void* d_out, int out_size, void* d_ws, size_t ws_size,
                              hipStream_t stream)
{
  (void)in_sizes; (void)n_in; (void)out_size; (void)ws_size;
  const float* x    = (const float*)d_in[0];
  const float* w1   = (const float*)d_in[1];
  const float* a1   = (const float*)d_in[2];
  const float* g1   = (const float*)d_in[3];
  const float* b1   = (const float*)d_in[4];
  const float* odw  = (const float*)d_in[5];
  const float* aodc = (const float*)d_in[6];
  const float* opw  = (const float*)d_in[7];
  const float* aopc = (const float*)d_in[8];
  const float* dww  = (const float*)d_in[9];
  const float* dwb  = (const float*)d_in[10];
  const float* a2   = (const float*)d_in[11];
  const float* g2   = (const float*)d_in[12];
  const float* b2   = (const float*)d_in[13];
  const float* pww  = (const float*)d_in[14];
  float* out = (float*)d_out;

  char* ws = (char*)d_ws;
  const size_t OFF_P1 = 0;          // part1 [M,250] float2: 16000 B
  const size_t OFF_P2 = 16384;      // part2 [M,500] float2: 32000 B
  const size_t OFF_DG = 49152;      // dotg2 [B] f32: 512 B
  const size_t OFF_DB = 49664;      // dotb2 [B] f32: 512 B
  const size_t OFF_WR = 50176;      // W2raw [B,H] bf16: 131072 B
  const size_t OFF_H  = 181248;     // Hbuf [M,T,H] bf16: 32768000 B
  const size_t OFF_Y  = 32949248;   // Ybuf [M,T,H] bf16: 32768000 B
  float2* part1  = (float2*)(ws + OFF_P1);
  float2* part2  = (float2*)(ws + OFF_P2);
  float*  dotg2  = (float*)(ws + OFF_DG);
  float*  dotb2  = (float*)(ws + OFF_DB);
  unsigned short* W2raw = (unsigned short*)(ws + OFF_WR);
  unsigned short* Hbuf  = (unsigned short*)(ws + OFF_H);
  unsigned short* Ybuf  = (unsigned short*)(ws + OFF_Y);

  k_prep  <<<dim3(128), 64, 0, stream>>>(g2, b2, pww, W2raw, dotg2, dotb2);
  k_conv1 <<<dim3(125, 2, 8), 256, 0, stream>>>(x, w1, a1, Hbuf, part1);
  k_deform<<<dim3(500, 8), 256, 0, stream>>>(Hbuf, part1, g1, b1, odw, aodc, opw, aopc, dww, dwb, a2, Ybuf, part2);
  k_out   <<<dim3(125, 2, 8), 256, 0, stream>>>(Ybuf, W2raw, part2, dotg2, dotb2, x, out);
}